// Round 1
// baseline (9420.415 us; speedup 1.0000x reference)
//
#include <hip/hip_runtime.h>
#include <math.h>

// Problem constants (fixed by reference)
#define Bb      16
#define Nn      15
#define Tt      50
#define Gg      4840
#define G2c     9680        // 2*G
#define BTc     800         // B*T
#define NNc     30          // 2*N
#define NITER   50
#define CHc     121         // g2 chunks for partial GEMM
#define CHUNKc  80          // G2c / CHc
#define NRANGES 40

// ---------------- helpers ----------------

__device__ __forceinline__ float a_elem(const float* __restrict__ Ar,
                                        const float* __restrict__ Ai,
                                        int n, int g2) {
    // A = [[Ar, -Ai], [Ai, Ar]]  -> [30, 9680]
    if (g2 < Gg) {
        return (n < Nn) ? Ar[n * Gg + g2] : Ai[(n - Nn) * Gg + g2];
    } else {
        int g = g2 - Gg;
        return (n < Nn) ? -Ai[n * Gg + g] : Ar[(n - Nn) * Gg + g];
    }
}

// ---------------- setup kernels ----------------

// At[g2*32 + n] = A[n][g2], cols 30,31 zero-padded (enables float4 row loads)
__global__ void build_at_kernel(const float* __restrict__ Ar, const float* __restrict__ Ai,
                                float* __restrict__ At) {
    int idx = blockIdx.x * 256 + threadIdx.x;
    if (idx >= G2c * 32) return;
    int g2 = idx >> 5, n = idx & 31;
    At[idx] = (n < NNc) ? a_elem(Ar, Ai, n, g2) : 0.f;
}

// M30[i][j] = sum_g2 A[i][g2]*A[j][g2]  (double accumulation), coalesced over g2
__global__ void gram_kernel(const float* __restrict__ Ar, const float* __restrict__ Ai,
                            double* __restrict__ M30) {
    int i = blockIdx.x / NNc, j = blockIdx.x % NNc;
    double acc = 0.0;
    for (int g2 = threadIdx.x; g2 < G2c; g2 += 256)
        acc += (double)a_elem(Ar, Ai, i, g2) * (double)a_elem(Ar, Ai, j, g2);
    __shared__ double red[256];
    red[threadIdx.x] = acc;
    __syncthreads();
    for (int s = 128; s > 0; s >>= 1) {
        if (threadIdx.x < s) red[threadIdx.x] += red[threadIdx.x + s];
        __syncthreads();
    }
    if (threadIdx.x == 0) M30[i * NNc + j] = red[0];
}

// Largest eigenvalue of M30 via repeated squaring (M^1024) + power + Rayleigh, fp64.
// One wave; lane i owns row i.
__global__ void power_kernel(const double* __restrict__ M30, float* __restrict__ st) {
    int lane = threadIdx.x;
    bool act = lane < NNc;
    double morig[NNc], cur[NNc];
    for (int j = 0; j < NNc; j++) {
        morig[j] = act ? M30[lane * NNc + j] : 0.0;
        cur[j] = morig[j];
    }
    __shared__ double Ms[NNc][NNc + 1];

    // normalize cur by max|entry|
    {
        double m = 0.0;
        for (int j = 0; j < NNc; j++) m = fmax(m, fabs(cur[j]));
        for (int o = 32; o > 0; o >>= 1) m = fmax(m, __shfl_xor(m, o, 64));
        for (int j = 0; j < NNc; j++) cur[j] /= m;
    }
    // 10 squarings -> (M/c)^1024
    for (int sq = 0; sq < 10; sq++) {
        if (act) for (int j = 0; j < NNc; j++) Ms[lane][j] = cur[j];
        __syncthreads();
        double nxt[NNc];
        for (int j = 0; j < NNc; j++) {
            double t = 0.0;
            for (int k = 0; k < NNc; k++) t += cur[k] * Ms[k][j];
            nxt[j] = t;
        }
        __syncthreads();
        double m = 0.0;
        for (int j = 0; j < NNc; j++) m = fmax(m, fabs(nxt[j]));
        for (int o = 32; o > 0; o >>= 1) m = fmax(m, __shfl_xor(m, o, 64));
        for (int j = 0; j < NNc; j++) cur[j] = nxt[j] / m;
    }
    // a few power steps with the massively-powered matrix
    double v = act ? (1.0 + 0.013 * lane) : 0.0;
    for (int it = 0; it < 4; it++) {
        double u = 0.0;
        for (int j = 0; j < NNc; j++) u += cur[j] * __shfl(v, j, 64);
        double n2 = u * u;
        for (int o = 32; o > 0; o >>= 1) n2 += __shfl_xor(n2, o, 64);
        v = u / sqrt(n2);
    }
    // Rayleigh quotient with ORIGINAL M (v unit norm)
    double u = 0.0;
    for (int j = 0; j < NNc; j++) u += morig[j] * __shfl(v, j, 64);
    double lam = u * v;
    for (int o = 32; o > 0; o >>= 1) lam += __shfl_xor(lam, o, 64);
    if (lane == 0) {
        float step = (float)((double)NNc / lam);  // 1/(lam/n)
        st[0] = step;
        st[1] = 0.01f * step;                      // MU * step
    }
}

// Aty[g2*800 + bt] = (1/30) * sum_n A[n][g2] * y[b][n][t]
__global__ void aty_kernel(const float* __restrict__ At, const float* __restrict__ yr,
                           const float* __restrict__ yi, float* __restrict__ Aty) {
    int idx = blockIdx.x * 256 + threadIdx.x;
    if (idx >= G2c * BTc) return;
    int g2 = idx / BTc, bt = idx - g2 * BTc;
    int b = bt / Tt, t = bt - b * Tt;
    const float* arow = At + g2 * 32;
    float acc = 0.f;
#pragma unroll
    for (int n = 0; n < Nn; n++) acc = fmaf(arow[n], yr[(b * Nn + n) * Tt + t], acc);
#pragma unroll
    for (int n = 0; n < Nn; n++) acc = fmaf(arow[Nn + n], yi[(b * Nn + n) * Tt + t], acc);
    Aty[idx] = acc / 30.f;
}

__global__ void zero_kernel(float4* __restrict__ X, int n4) {
    int idx = blockIdx.x * 256 + threadIdx.x;
    if (idx < n4) X[idx] = make_float4(0.f, 0.f, 0.f, 0.f);
}

// ---------------- ISTA iteration kernels ----------------

// Partial Ax: Axp[(c*800+bt)*32 + n] = sum_{g2 in chunk c} A[n][g2]*X[g2][bt]
__global__ __launch_bounds__(448) void gemm_partial_kernel(const float* __restrict__ At,
                                                           const float* __restrict__ X,
                                                           float* __restrict__ Axp) {
    int tid = threadIdx.x;
    if (tid >= 400) return;
    int bt = blockIdx.y * 400 + tid;
    int c = blockIdx.x;
    float acc[32];
#pragma unroll
    for (int n = 0; n < 32; n++) acc[n] = 0.f;
    int g2_0 = c * CHUNKc;
    for (int k = 0; k < CHUNKc; k++) {
        int g2 = g2_0 + k;
        const float4* av = (const float4*)(At + (size_t)g2 * 32);
        float xv = X[(size_t)g2 * BTc + bt];
#pragma unroll
        for (int q = 0; q < 8; q++) {
            float4 a = av[q];
            acc[4 * q + 0] = fmaf(a.x, xv, acc[4 * q + 0]);
            acc[4 * q + 1] = fmaf(a.y, xv, acc[4 * q + 1]);
            acc[4 * q + 2] = fmaf(a.z, xv, acc[4 * q + 2]);
            acc[4 * q + 3] = fmaf(a.w, xv, acc[4 * q + 3]);
        }
    }
    float4* outp = (float4*)(Axp + ((size_t)c * BTc + bt) * 32);
#pragma unroll
    for (int q = 0; q < 8; q++)
        outp[q] = make_float4(acc[4 * q], acc[4 * q + 1], acc[4 * q + 2], acc[4 * q + 3]);
}

// Axt[bt*32 + n] = sum_c Axp[c][bt][n]
__global__ void reduce_kernel(const float* __restrict__ Axp, float* __restrict__ Axt) {
    int j = blockIdx.x * 256 + threadIdx.x;  // < 25600
    float acc = 0.f;
    for (int c = 0; c < CHc; c++) acc += Axp[(size_t)c * BTc * 32 + j];
    Axt[j] = acc;
}

// grad = (1/30)*sum_n A[n][g2]*Ax[n][bt] - Aty; x = soft(x - step*grad, thr)
__global__ void update_kernel(const float* __restrict__ At, const float* __restrict__ Axt,
                              const float* __restrict__ Aty, float* __restrict__ X,
                              const float* __restrict__ st) {
    int idx = blockIdx.x * 256 + threadIdx.x;
    if (idx >= G2c * BTc) return;
    int g2 = idx / BTc, bt = idx - g2 * BTc;
    const float4* av = (const float4*)(At + (size_t)g2 * 32);
    const float4* wv = (const float4*)(Axt + (size_t)bt * 32);
    float dot = 0.f;
#pragma unroll
    for (int q = 0; q < 8; q++) {
        float4 a = av[q];
        float4 w = wv[q];
        dot = fmaf(a.x, w.x, dot);
        dot = fmaf(a.y, w.y, dot);
        dot = fmaf(a.z, w.z, dot);
        dot = fmaf(a.w, w.w, dot);
    }
    float step = st[0], thr = st[1];
    float grad = dot / 30.f - Aty[idx];
    float v = X[idx] - step * grad;
    float m = fabsf(v) - thr;
    X[idx] = (m > 0.f) ? copysignf(m, v) : 0.f;
}

// ---------------- epilogue kernels ----------------

// npart[c*800 + bt] = sum_{g in chunk c of 121} sqrt(xr^2 + xi^2 + 1e-12)
__global__ __launch_bounds__(832) void norms_partial_kernel(const float* __restrict__ X,
                                                            float* __restrict__ npart) {
    int tid = threadIdx.x;
    if (tid >= BTc) return;
    int c = blockIdx.x;  // 0..39
    int g0 = c * 121;
    float acc = 0.f;
    for (int k = 0; k < 121; k++) {
        int g = g0 + k;
        float xr = X[(size_t)g * BTc + tid];
        float xi = X[(size_t)(Gg + g) * BTc + tid];
        acc += sqrtf(fmaf(xr, xr, fmaf(xi, xi, 1e-12f)));
    }
    npart[c * BTc + tid] = acc;
}

// norms[bt] = sum_c npart; midx[b] = argmin_t norms[b*50+t] (first min)
__global__ __launch_bounds__(832) void argmin_kernel(const float* __restrict__ npart,
                                                     int* __restrict__ midx) {
    __shared__ float norms[BTc];
    int tid = threadIdx.x;
    if (tid < BTc) {
        float acc = 0.f;
        for (int c = 0; c < 40; c++) acc += npart[c * BTc + tid];
        norms[tid] = acc;
    }
    __syncthreads();
    if (tid < Bb) {
        float best = norms[tid * Tt];
        int bi = 0;
        for (int t = 1; t < Tt; t++) {
            float v = norms[tid * Tt + t];
            if (v < best) { best = v; bi = t; }
        }
        midx[tid] = bi;
    }
}

// s[b][g] = (1/16) * sum_j sqrt(x[g][b*50+tj]^2 + x[G+g][b*50+tj]^2 + 1e-12)
__global__ void s_kernel(const float* __restrict__ X, const int* __restrict__ midx,
                         float* __restrict__ out_s) {
    __shared__ int mi[Bb];
    if (threadIdx.x < Bb) mi[threadIdx.x] = midx[threadIdx.x];
    __syncthreads();
    int idx = blockIdx.x * 256 + threadIdx.x;
    if (idx >= Bb * Gg) return;
    int b = idx / Gg, g = idx - b * Gg;
    float acc = 0.f;
#pragma unroll
    for (int j = 0; j < Bb; j++) {
        int bt = b * Tt + mi[j];
        float xr = X[(size_t)g * BTc + bt];
        float xi = X[(size_t)(Gg + g) * BTc + bt];
        acc += sqrtf(fmaf(xr, xr, fmaf(xi, xi, 1e-12f)));
    }
    out_s[idx] = acc * (1.f / 16.f);
}

__device__ __forceinline__ bool better_pair(float v, int i, float bv, int bi) {
    return (v > bv) || (v == bv && i < bi);
}

// Stable top-2 per batch (lax.top_k semantics: descending, ties -> lower index)
__global__ void top2_kernel(const float* __restrict__ out_s, const float* __restrict__ angles,
                            const float* __restrict__ ranges, float* __restrict__ out) {
    int b = blockIdx.x, tid = threadIdx.x;
    const float* sb = out_s + (size_t)b * Gg;
    float v1 = -INFINITY, v2 = -INFINITY;
    int i1 = 0x7fffffff, i2 = 0x7fffffff;
    for (int g = tid; g < Gg; g += 256) {
        float v = sb[g];
        if (better_pair(v, g, v1, i1)) { v2 = v1; i2 = i1; v1 = v; i1 = g; }
        else if (better_pair(v, g, v2, i2)) { v2 = v; i2 = g; }
    }
    __shared__ float sv1[256], sv2[256];
    __shared__ int si1[256], si2[256];
    sv1[tid] = v1; si1[tid] = i1; sv2[tid] = v2; si2[tid] = i2;
    __syncthreads();
    for (int stp = 128; stp > 0; stp >>= 1) {
        if (tid < stp) {
            float a1 = sv1[tid], a2 = sv2[tid];
            int ai1 = si1[tid], ai2 = si2[tid];
            float b1 = sv1[tid + stp], b2 = sv2[tid + stp];
            int bi1 = si1[tid + stp], bi2 = si2[tid + stp];
            float n1, n2;
            int ni1, ni2;
            if (better_pair(b1, bi1, a1, ai1)) {
                n1 = b1; ni1 = bi1;
                if (better_pair(a1, ai1, b2, bi2)) { n2 = a1; ni2 = ai1; }
                else { n2 = b2; ni2 = bi2; }
            } else {
                n1 = a1; ni1 = ai1;
                if (better_pair(b1, bi1, a2, ai2)) { n2 = b1; ni2 = bi1; }
                else { n2 = a2; ni2 = ai2; }
            }
            sv1[tid] = n1; si1[tid] = ni1; sv2[tid] = n2; si2[tid] = ni2;
        }
        __syncthreads();
    }
    if (tid == 0) {
        int ia = si1[0], ib2 = si2[0];
        // out layout: doa[16][2] | rng[16][2] | s[16][4840]
        out[b * 2 + 0] = angles[ia / NRANGES];
        out[b * 2 + 1] = angles[ib2 / NRANGES];
        out[32 + b * 2 + 0] = ranges[ia % NRANGES];
        out[32 + b * 2 + 1] = ranges[ib2 % NRANGES];
    }
}

// ---------------- launch ----------------

extern "C" void kernel_launch(void* const* d_in, const int* in_sizes, int n_in,
                              void* d_out, int out_size, void* d_ws, size_t ws_size,
                              hipStream_t stream) {
    const float* yr = (const float*)d_in[0];      // [16,15,50]
    const float* yi = (const float*)d_in[1];      // [16,15,50]
    const float* Ar = (const float*)d_in[2];      // [15,4840]
    const float* Ai = (const float*)d_in[3];      // [15,4840]
    const float* angles = (const float*)d_in[4];  // [121]
    const float* ranges = (const float*)d_in[5];  // [40]
    float* out = (float*)d_out;                   // 32 doa + 32 rng + 77440 s
    float* w = (float*)d_ws;

    // workspace layout (floats); total ~72.3 MB
    size_t oAt = 0;                                   // 9680*32   = 309760
    size_t oAty = oAt + (size_t)G2c * 32;             // 7744000
    size_t oX = oAty + (size_t)G2c * BTc;             // 7744000
    size_t oAxp = oX + (size_t)G2c * BTc;             // 121*800*32 = 3097600
    size_t oAxt = oAxp + (size_t)CHc * BTc * 32;      // 25600
    size_t oM30 = oAxt + (size_t)BTc * 32;            // 900 doubles (8B-aligned: offset even)
    size_t oSt = oM30 + 1800;                         // 4
    size_t oNp = oSt + 4;                             // 40*800 = 32000
    size_t oMidx = oNp + 40 * BTc;                    // 16 ints

    float* At = w + oAt;
    float* Aty = w + oAty;
    float* X = w + oX;
    float* Axp = w + oAxp;
    float* Axt = w + oAxt;
    double* M30 = (double*)(w + oM30);
    float* st = w + oSt;
    float* npart = w + oNp;
    int* midx = (int*)(w + oMidx);

    build_at_kernel<<<(G2c * 32) / 256, 256, 0, stream>>>(Ar, Ai, At);
    gram_kernel<<<NNc * NNc, 256, 0, stream>>>(Ar, Ai, M30);
    power_kernel<<<1, 64, 0, stream>>>(M30, st);
    aty_kernel<<<(G2c * BTc + 255) / 256, 256, 0, stream>>>(At, yr, yi, Aty);
    zero_kernel<<<(G2c * BTc / 4 + 255) / 256, 256, 0, stream>>>((float4*)X, G2c * BTc / 4);

    for (int it = 0; it < NITER; it++) {
        gemm_partial_kernel<<<dim3(CHc, 2), 448, 0, stream>>>(At, X, Axp);
        reduce_kernel<<<(BTc * 32) / 256, 256, 0, stream>>>(Axp, Axt);
        update_kernel<<<(G2c * BTc + 255) / 256, 256, 0, stream>>>(At, Axt, Aty, X, st);
    }

    norms_partial_kernel<<<40, 832, 0, stream>>>(X, npart);
    argmin_kernel<<<1, 832, 0, stream>>>(npart, midx);
    s_kernel<<<(Bb * Gg + 255) / 256, 256, 0, stream>>>(X, midx, out + 64);
    top2_kernel<<<Bb, 256, 0, stream>>>(out + 64, angles, ranges, out);
}

// Round 2
// 7227.325 us; speedup vs baseline: 1.3034x; 1.3034x over previous
//
#include <hip/hip_runtime.h>
#include <math.h>

// Problem constants (fixed by reference)
#define Bb      16
#define Nn      15
#define Tt      50
#define Gg      4840
#define G2c     9680        // 2*G
#define G2P     9728        // padded rows = 128*76
#define BTc     800         // B*T
#define NNc     30          // 2*N
#define NITER   50
#define NRANGES 40

// fused-solver geometry
#define NB      200         // blocks = 800 columns / 4
#define CPB     4           // columns per block
#define TPB     512         // threads per block
#define TPC     128         // threads per column
#define ROWS    76          // G2P / TPC
#define NGI     38          // norm loop steps (38*128 >= 4840)

// ---------------- helpers ----------------

__device__ __forceinline__ float a_elem(const float* __restrict__ Ar,
                                        const float* __restrict__ Ai,
                                        int n, int g2) {
    // A = [[Ar, -Ai], [Ai, Ar]]  -> [30, 9680]
    if (g2 < Gg) {
        return (n < Nn) ? Ar[n * Gg + g2] : Ai[(n - Nn) * Gg + g2];
    } else {
        int g = g2 - Gg;
        return (n < Nn) ? -Ai[n * Gg + g] : Ar[(n - Nn) * Gg + g];
    }
}

// ---------------- setup kernels ----------------

// AtP[r*32 + n] = A[n][r]; rows >= 9680 and cols >= 30 zero-padded
__global__ void build_at_kernel(const float* __restrict__ Ar, const float* __restrict__ Ai,
                                float* __restrict__ AtP) {
    int idx = blockIdx.x * 256 + threadIdx.x;
    if (idx >= G2P * 32) return;
    int r = idx >> 5, n = idx & 31;
    AtP[idx] = (r < G2c && n < NNc) ? a_elem(Ar, Ai, n, r) : 0.f;
}

// M30[i][j] = sum_g2 A[i][g2]*A[j][g2]  (double accumulation), coalesced over g2
__global__ void gram_kernel(const float* __restrict__ Ar, const float* __restrict__ Ai,
                            double* __restrict__ M30) {
    int i = blockIdx.x / NNc, j = blockIdx.x % NNc;
    double acc = 0.0;
    for (int g2 = threadIdx.x; g2 < G2c; g2 += 256)
        acc += (double)a_elem(Ar, Ai, i, g2) * (double)a_elem(Ar, Ai, j, g2);
    __shared__ double red[256];
    red[threadIdx.x] = acc;
    __syncthreads();
    for (int s = 128; s > 0; s >>= 1) {
        if (threadIdx.x < s) red[threadIdx.x] += red[threadIdx.x + s];
        __syncthreads();
    }
    if (threadIdx.x == 0) M30[i * NNc + j] = red[0];
}

// Largest eigenvalue of the 30x30 Gram via 10 LDS matrix squarings (M^1024),
// dominant eigvec = column 0, then Rayleigh with original M. fp64, 1024 threads.
__global__ void step_kernel(const double* __restrict__ M30, float* __restrict__ st) {
    __shared__ double M0[NNc][NNc];
    __shared__ double Mc[NNc][NNc];
    __shared__ double s[1024];
    int tid = threadIdx.x;
    int i = tid / NNc, j = tid - i * NNc;
    bool act = tid < NNc * NNc;
    if (act) M0[i][j] = M30[tid];
    __syncthreads();
    s[tid] = act ? fabs(M0[i][j]) : 0.0;
    __syncthreads();
    for (int o = 512; o; o >>= 1) {
        if (tid < o) s[tid] = fmax(s[tid], s[tid + o]);
        __syncthreads();
    }
    double mx = s[0];
    __syncthreads();
    if (act) Mc[i][j] = M0[i][j] / mx;
    __syncthreads();
    for (int sq = 0; sq < 10; sq++) {
        double t = 0.0;
        if (act) {
            for (int k = 0; k < NNc; k++) t += Mc[i][k] * Mc[k][j];
        }
        s[tid] = act ? fabs(t) : 0.0;
        __syncthreads();
        for (int o = 512; o; o >>= 1) {
            if (tid < o) s[tid] = fmax(s[tid], s[tid + o]);
            __syncthreads();
        }
        double m2 = s[0];
        __syncthreads();
        if (act) Mc[i][j] = t / m2;
        __syncthreads();
    }
    // Rayleigh quotient with v = Mc[:,0]
    s[tid] = act ? Mc[i][0] * M0[i][j] * Mc[j][0] : 0.0;
    __syncthreads();
    for (int o = 512; o; o >>= 1) {
        if (tid < o) s[tid] += s[tid + o];
        __syncthreads();
    }
    double num = s[0];
    __syncthreads();
    s[tid] = (tid < NNc) ? Mc[tid][0] * Mc[tid][0] : 0.0;
    __syncthreads();
    for (int o = 512; o; o >>= 1) {
        if (tid < o) s[tid] += s[tid + o];
        __syncthreads();
    }
    double den = s[0];
    if (tid == 0) {
        double lam = num / den;              // sigma_max(A)^2
        double step = (double)NNc / lam;     // 1 / (lam/30)
        st[0] = (float)step;
        st[1] = (float)(0.01 * step);        // MU * step
        st[2] = (float)(step / 30.0);        // folded scale for Aty and Ax
    }
}

// ys[bt*32 + n] = (step/30) * stacked y; pads (n>=30) zero
__global__ void ys_kernel(const float* __restrict__ yr, const float* __restrict__ yi,
                          const float* __restrict__ st, float* __restrict__ ys) {
    int idx = blockIdx.x * 256 + threadIdx.x;
    if (idx >= BTc * 32) return;
    int bt = idx >> 5, n = idx & 31;
    int b = bt / Tt, t = bt - b * Tt;
    float v = 0.f;
    if (n < Nn) v = yr[(b * Nn + n) * Tt + t];
    else if (n < NNc) v = yi[(b * Nn + (n - Nn)) * Tt + t];
    ys[idx] = st[2] * v;
}

// AtyS[bt*9728 + r] = sum_n AtP[r][n] * ys[bt][n]   ( = step * Aty / 1 )
__global__ void atys_kernel(const float* __restrict__ AtP, const float* __restrict__ ys,
                            float* __restrict__ AtyS) {
    int idx = blockIdx.x * 256 + threadIdx.x;
    if (idx >= BTc * G2P) return;
    int bt = idx / G2P, r = idx - bt * G2P;
    const float4* av = (const float4*)(AtP + (size_t)r * 32);
    const float4* yv = (const float4*)(ys + (size_t)bt * 32);
    float acc = 0.f;
#pragma unroll
    for (int q = 0; q < 8; q++) {
        float4 a = av[q];
        float4 y = yv[q];
        acc = fmaf(a.x, y.x, acc);
        acc = fmaf(a.y, y.y, acc);
        acc = fmaf(a.z, y.z, acc);
        acc = fmaf(a.w, y.w, acc);
    }
    AtyS[idx] = acc;
}

// ---------------- fused ISTA solver ----------------
// One block owns 4 (b,t) columns for all 50 iterations. X lives in LDS.
// Per iteration, one pass over rows fuses: x_new = soft(x - At.axb + AtyS)
// and acc += At * x_new (the next iteration's Ax). axb = (step/30)*Ax.
__global__ __launch_bounds__(TPB, 2) void ista_kernel(
    const float* __restrict__ AtP, const float* __restrict__ AtyS,
    const float* __restrict__ st, float* __restrict__ Xg,
    float* __restrict__ norms_g) {
    __shared__ float Xl[CPB][G2P];   // 155,648 B
    __shared__ float axb[CPB][32];
    __shared__ float red[8][32];
    int tid = threadIdx.x;
    int b4 = blockIdx.x;
    int c = tid >> 7;         // column group 0..3
    int lane = tid & 127;     // position within column group
    int wv = tid >> 6;        // wave 0..7 (waves 2c, 2c+1 belong to column c)
    int wl = tid & 63;
    int bt = b4 * CPB + c;
    float thr = st[1], st2 = st[2];

    for (int k = tid; k < CPB * G2P; k += TPB) ((float*)Xl)[k] = 0.f;
    if (tid < CPB * 32) ((float*)axb)[tid] = 0.f;
    __syncthreads();

    const float* atyp = AtyS + (size_t)bt * G2P;

    for (int it = 0; it < NITER; it++) {
        float axr[NNc];
#pragma unroll
        for (int n = 0; n < NNc; n++) axr[n] = axb[c][n];
        float acc[NNc];
#pragma unroll
        for (int n = 0; n < NNc; n++) acc[n] = 0.f;

        for (int i = 0; i < ROWS; i++) {
            int r = i * TPC + lane;
            const float4* ap = (const float4*)(AtP + (size_t)r * 32);
            float atv[32];
#pragma unroll
            for (int q = 0; q < 8; q++) ((float4*)atv)[q] = ap[q];
            float aty = atyp[r];
            float x = Xl[c][r];
            float d0 = 0.f, d1 = 0.f;
#pragma unroll
            for (int n = 0; n < NNc; n += 2) {
                d0 = fmaf(atv[n], axr[n], d0);
                d1 = fmaf(atv[n + 1], axr[n + 1], d1);
            }
            float v = x - (d0 + d1) + aty;
            float m = fabsf(v) - thr;
            float xn = (m > 0.f) ? copysignf(m, v) : 0.f;
            Xl[c][r] = xn;
#pragma unroll
            for (int n = 0; n < NNc; n++) acc[n] = fmaf(atv[n], xn, acc[n]);
            if ((i & 7) == 7) __syncthreads();  // keep the 4 groups' At windows L1-aligned
        }
        if (it == NITER - 1) break;
        // reduce acc over the 2 waves of this column
#pragma unroll
        for (int n = 0; n < NNc; n++) {
            acc[n] += __shfl_xor(acc[n], 32, 64);
            acc[n] += __shfl_xor(acc[n], 16, 64);
            acc[n] += __shfl_xor(acc[n], 8, 64);
            acc[n] += __shfl_xor(acc[n], 4, 64);
            acc[n] += __shfl_xor(acc[n], 2, 64);
            acc[n] += __shfl_xor(acc[n], 1, 64);
        }
        if (wl == 0) {
#pragma unroll
            for (int n = 0; n < NNc; n++) red[wv][n] = acc[n];
        }
        __syncthreads();
        if (tid < CPB * NNc) {
            int c2 = tid / NNc, n = tid - c2 * NNc;
            axb[c2][n] = (red[2 * c2][n] + red[2 * c2 + 1][n]) * st2;
        }
        __syncthreads();
    }
    __syncthreads();

    // write back X (layout Xg[bt][9680])
    for (int i = 0; i < ROWS; i++) {
        int r = i * TPC + lane;
        if (r < G2c) Xg[(size_t)bt * G2c + r] = Xl[c][r];
    }
    // per-column L1 norm of magnitudes
    float na = 0.f;
    for (int i = 0; i < NGI; i++) {
        int g = i * TPC + lane;
        if (g < Gg) {
            float xr = Xl[c][g], xi = Xl[c][g + Gg];
            na += sqrtf(fmaf(xr, xr, fmaf(xi, xi, 1e-12f)));
        }
    }
    for (int o = 32; o; o >>= 1) na += __shfl_xor(na, o, 64);
    if (wl == 0) red[wv][0] = na;
    __syncthreads();
    if (tid < CPB) norms_g[b4 * CPB + tid] = red[2 * tid][0] + red[2 * tid + 1][0];
}

// ---------------- epilogue kernels ----------------

__global__ __launch_bounds__(832) void argmin_kernel(const float* __restrict__ norms_g,
                                                     int* __restrict__ midx) {
    __shared__ float norms[BTc];
    int tid = threadIdx.x;
    if (tid < BTc) norms[tid] = norms_g[tid];
    __syncthreads();
    if (tid < Bb) {
        float best = norms[tid * Tt];
        int bi = 0;
        for (int t = 1; t < Tt; t++) {
            float v = norms[tid * Tt + t];
            if (v < best) { best = v; bi = t; }
        }
        midx[tid] = bi;
    }
}

// s[b][g] = (1/16) * sum_j sqrt(x[g][b*50+tj]^2 + x[G+g][b*50+tj]^2 + 1e-12)
__global__ void s_kernel(const float* __restrict__ Xg, const int* __restrict__ midx,
                         float* __restrict__ out_s) {
    __shared__ int mi[Bb];
    if (threadIdx.x < Bb) mi[threadIdx.x] = midx[threadIdx.x];
    __syncthreads();
    int idx = blockIdx.x * 256 + threadIdx.x;
    if (idx >= Bb * Gg) return;
    int b = idx / Gg, g = idx - b * Gg;
    float acc = 0.f;
#pragma unroll
    for (int j = 0; j < Bb; j++) {
        int bt = b * Tt + mi[j];
        float xr = Xg[(size_t)bt * G2c + g];
        float xi = Xg[(size_t)bt * G2c + Gg + g];
        acc += sqrtf(fmaf(xr, xr, fmaf(xi, xi, 1e-12f)));
    }
    out_s[idx] = acc * (1.f / 16.f);
}

__device__ __forceinline__ bool better_pair(float v, int i, float bv, int bi) {
    return (v > bv) || (v == bv && i < bi);
}

// Stable top-2 per batch (lax.top_k semantics: descending, ties -> lower index)
__global__ void top2_kernel(const float* __restrict__ out_s, const float* __restrict__ angles,
                            const float* __restrict__ ranges, float* __restrict__ out) {
    int b = blockIdx.x, tid = threadIdx.x;
    const float* sb = out_s + (size_t)b * Gg;
    float v1 = -INFINITY, v2 = -INFINITY;
    int i1 = 0x7fffffff, i2 = 0x7fffffff;
    for (int g = tid; g < Gg; g += 256) {
        float v = sb[g];
        if (better_pair(v, g, v1, i1)) { v2 = v1; i2 = i1; v1 = v; i1 = g; }
        else if (better_pair(v, g, v2, i2)) { v2 = v; i2 = g; }
    }
    __shared__ float sv1[256], sv2[256];
    __shared__ int si1[256], si2[256];
    sv1[tid] = v1; si1[tid] = i1; sv2[tid] = v2; si2[tid] = i2;
    __syncthreads();
    for (int stp = 128; stp > 0; stp >>= 1) {
        if (tid < stp) {
            float a1 = sv1[tid], a2 = sv2[tid];
            int ai1 = si1[tid], ai2 = si2[tid];
            float b1 = sv1[tid + stp], b2 = sv2[tid + stp];
            int bi1 = si1[tid + stp], bi2 = si2[tid + stp];
            float n1, n2;
            int ni1, ni2;
            if (better_pair(b1, bi1, a1, ai1)) {
                n1 = b1; ni1 = bi1;
                if (better_pair(a1, ai1, b2, bi2)) { n2 = a1; ni2 = ai1; }
                else { n2 = b2; ni2 = bi2; }
            } else {
                n1 = a1; ni1 = ai1;
                if (better_pair(b1, bi1, a2, ai2)) { n2 = b1; ni2 = bi1; }
                else { n2 = a2; ni2 = ai2; }
            }
            sv1[tid] = n1; si1[tid] = ni1; sv2[tid] = n2; si2[tid] = ni2;
        }
        __syncthreads();
    }
    if (tid == 0) {
        int ia = si1[0], ib2 = si2[0];
        // out layout: doa[16][2] | rng[16][2] | s[16][4840]
        out[b * 2 + 0] = angles[ia / NRANGES];
        out[b * 2 + 1] = angles[ib2 / NRANGES];
        out[32 + b * 2 + 0] = ranges[ia % NRANGES];
        out[32 + b * 2 + 1] = ranges[ib2 % NRANGES];
    }
}

// ---------------- launch ----------------

extern "C" void kernel_launch(void* const* d_in, const int* in_sizes, int n_in,
                              void* d_out, int out_size, void* d_ws, size_t ws_size,
                              hipStream_t stream) {
    const float* yr = (const float*)d_in[0];      // [16,15,50]
    const float* yi = (const float*)d_in[1];      // [16,15,50]
    const float* Ar = (const float*)d_in[2];      // [15,4840]
    const float* Ai = (const float*)d_in[3];      // [15,4840]
    const float* angles = (const float*)d_in[4];  // [121]
    const float* ranges = (const float*)d_in[5];  // [40]
    float* out = (float*)d_out;                   // 32 doa + 32 rng + 77440 s
    float* w = (float*)d_ws;

    // workspace layout (floats), ~63.5 MB total
    size_t oAtP = 0;                               // 9728*32 = 311296
    size_t oM30 = oAtP + (size_t)G2P * 32;         // 900 doubles (byte ofs 8-aligned)
    size_t oSt = oM30 + 1800;                      // 8
    size_t oYs = oSt + 8;                          // 800*32 = 25600
    size_t oAtyS = oYs + (size_t)BTc * 32;         // 800*9728 = 7782400
    size_t oXg = oAtyS + (size_t)BTc * G2P;        // 800*9680 = 7744000
    size_t oNrm = oXg + (size_t)BTc * G2c;         // 800
    size_t oMidx = oNrm + BTc;                     // 16 ints

    float* AtP = w + oAtP;
    double* M30 = (double*)(w + oM30);
    float* st = w + oSt;
    float* ys = w + oYs;
    float* AtyS = w + oAtyS;
    float* Xg = w + oXg;
    float* norms_g = w + oNrm;
    int* midx = (int*)(w + oMidx);

    build_at_kernel<<<(G2P * 32) / 256, 256, 0, stream>>>(Ar, Ai, AtP);
    gram_kernel<<<NNc * NNc, 256, 0, stream>>>(Ar, Ai, M30);
    step_kernel<<<1, 1024, 0, stream>>>(M30, st);
    ys_kernel<<<(BTc * 32) / 256, 256, 0, stream>>>(yr, yi, st, ys);
    atys_kernel<<<(BTc * G2P) / 256, 256, 0, stream>>>(AtP, ys, AtyS);

    ista_kernel<<<NB, TPB, 0, stream>>>(AtP, AtyS, st, Xg, norms_g);

    argmin_kernel<<<1, 832, 0, stream>>>(norms_g, midx);
    s_kernel<<<(Bb * Gg + 255) / 256, 256, 0, stream>>>(Xg, midx, out + 64);
    top2_kernel<<<Bb, 256, 0, stream>>>(out + 64, angles, ranges, out);
}

// Round 3
// 1774.504 us; speedup vs baseline: 5.3088x; 4.0729x over previous
//
#include <hip/hip_runtime.h>
#include <math.h>

// Problem constants (fixed by reference)
#define Bb      16
#define Nn      15
#define Tt      50
#define Gg      4840
#define G2c     9680        // 2*G
#define BTc     800         // B*T
#define NNc     30          // 2*N
#define NITER   50
#define NRANGES 40

// fused-solver geometry
#define G64     76          // 64-g chunks (76*64 = 4864 >= 4840)
#define GP      4864        // padded grid points
#define NB      200         // blocks = 800 columns / 4
#define CPB     4           // columns per block
#define TPB     512         // threads: 2 sets x 256; each thread: 1 g, 2 cols

// ---------------- setup kernels ----------------

// ArW[chunk*960 + k*64 + l] = Ar[k][chunk*64+l]  (zero-padded past Gg)
__global__ void repack_a_kernel(const float* __restrict__ Ar, const float* __restrict__ Ai,
                                float* __restrict__ ArW, float* __restrict__ AiW) {
    int idx = blockIdx.x * 256 + threadIdx.x;
    if (idx >= G64 * 960) return;
    int chunk = idx / 960, rem = idx - chunk * 960;
    int k = rem >> 6, l = rem & 63;
    int g = chunk * 64 + l;
    float vr = 0.f, vi = 0.f;
    if (g < Gg) { vr = Ar[k * Gg + g]; vi = Ai[k * Gg + g]; }
    ArW[idx] = vr;
    AiW[idx] = vi;
}

__device__ __forceinline__ float a_elem(const float* __restrict__ Ar,
                                        const float* __restrict__ Ai,
                                        int n, int g2) {
    if (g2 < Gg) {
        return (n < Nn) ? Ar[n * Gg + g2] : Ai[(n - Nn) * Gg + g2];
    } else {
        int g = g2 - Gg;
        return (n < Nn) ? -Ai[n * Gg + g] : Ar[(n - Nn) * Gg + g];
    }
}

// M30[i][j] = sum_g2 A[i][g2]*A[j][g2]  (double accumulation), coalesced over g2
__global__ void gram_kernel(const float* __restrict__ Ar, const float* __restrict__ Ai,
                            double* __restrict__ M30) {
    int i = blockIdx.x / NNc, j = blockIdx.x % NNc;
    double acc = 0.0;
    for (int g2 = threadIdx.x; g2 < G2c; g2 += 256)
        acc += (double)a_elem(Ar, Ai, i, g2) * (double)a_elem(Ar, Ai, j, g2);
    __shared__ double red[256];
    red[threadIdx.x] = acc;
    __syncthreads();
    for (int s = 128; s > 0; s >>= 1) {
        if (threadIdx.x < s) red[threadIdx.x] += red[threadIdx.x + s];
        __syncthreads();
    }
    if (threadIdx.x == 0) M30[i * NNc + j] = red[0];
}

// Largest eigenvalue of the 30x30 Gram via 10 LDS matrix squarings (M^1024),
// dominant eigvec = column 0, then Rayleigh with original M. fp64, 1024 threads.
__global__ void step_kernel(const double* __restrict__ M30, float* __restrict__ st) {
    __shared__ double M0[NNc][NNc];
    __shared__ double Mc[NNc][NNc];
    __shared__ double s[1024];
    int tid = threadIdx.x;
    int i = tid / NNc, j = tid - i * NNc;
    bool act = tid < NNc * NNc;
    if (act) M0[i][j] = M30[tid];
    __syncthreads();
    s[tid] = act ? fabs(M0[i][j]) : 0.0;
    __syncthreads();
    for (int o = 512; o; o >>= 1) {
        if (tid < o) s[tid] = fmax(s[tid], s[tid + o]);
        __syncthreads();
    }
    double mx = s[0];
    __syncthreads();
    if (act) Mc[i][j] = M0[i][j] / mx;
    __syncthreads();
    for (int sq = 0; sq < 10; sq++) {
        double t = 0.0;
        if (act) {
            for (int k = 0; k < NNc; k++) t += Mc[i][k] * Mc[k][j];
        }
        s[tid] = act ? fabs(t) : 0.0;
        __syncthreads();
        for (int o = 512; o; o >>= 1) {
            if (tid < o) s[tid] = fmax(s[tid], s[tid + o]);
            __syncthreads();
        }
        double m2 = s[0];
        __syncthreads();
        if (act) Mc[i][j] = t / m2;
        __syncthreads();
    }
    s[tid] = act ? Mc[i][0] * M0[i][j] * Mc[j][0] : 0.0;
    __syncthreads();
    for (int o = 512; o; o >>= 1) {
        if (tid < o) s[tid] += s[tid + o];
        __syncthreads();
    }
    double num = s[0];
    __syncthreads();
    s[tid] = (tid < NNc) ? Mc[tid][0] * Mc[tid][0] : 0.0;
    __syncthreads();
    for (int o = 512; o; o >>= 1) {
        if (tid < o) s[tid] += s[tid + o];
        __syncthreads();
    }
    double den = s[0];
    if (tid == 0) {
        double lam = num / den;              // sigma_max(A)^2
        double step = (double)NNc / lam;     // 1 / (lam/30)
        st[0] = (float)step;
        st[1] = (float)(0.01 * step);        // MU * step
        st[2] = (float)(step / 30.0);        // folded scale for Aty and Ax
    }
}

// AtyW[bt][g][0/1] = step*Aty for real/imag rows, interleaved; pads zero.
__global__ void atys_kernel(const float* __restrict__ Ar, const float* __restrict__ Ai,
                            const float* __restrict__ yr, const float* __restrict__ yi,
                            const float* __restrict__ st, float* __restrict__ AtyW) {
    int bt = blockIdx.x;
    int b = bt / Tt, t = bt - b * Tt;
    __shared__ float ysr[Nn], ysi[Nn];
    int tid = threadIdx.x;
    if (tid < Nn) {
        float s2 = st[2];
        ysr[tid] = s2 * yr[(b * Nn + tid) * Tt + t];
        ysi[tid] = s2 * yi[(b * Nn + tid) * Tt + t];
    }
    __syncthreads();
    for (int g = tid; g < GP; g += 256) {
        float accR = 0.f, accI = 0.f;
        if (g < Gg) {
#pragma unroll
            for (int k = 0; k < Nn; k++) {
                float a = Ar[k * Gg + g], c = Ai[k * Gg + g];
                accR = fmaf(a, ysr[k], accR);
                accR = fmaf(c, ysi[k], accR);
                accI = fmaf(-c, ysr[k], accI);
                accI = fmaf(a, ysi[k], accI);
            }
        }
        float2* p = (float2*)(AtyW + (size_t)bt * (2 * GP) + 2 * g);
        *p = make_float2(accR, accI);
    }
}

// ---------------- fused ISTA solver ----------------
// Block owns 4 columns; 2 thread-sets of 256, each set handles 2 columns.
// Thread owns grid point g = step*256 + l256 (per step), computes both the
// real row g and imag row G+g from one load of (Ar[:,g], Ai[:,g]).
__global__ __launch_bounds__(TPB, 2) void ista_kernel(
    const float* __restrict__ ArW, const float* __restrict__ AiW,
    const float* __restrict__ AtyW, const float* __restrict__ st,
    float* __restrict__ Xg, float* __restrict__ norms_g) {
    __shared__ float Xli[CPB][GP * 2];   // 155,648 B, [c][g][re,im]
    __shared__ float axb[CPB][32];
    __shared__ float red[8][64];
    int tid = threadIdx.x;
    int sset = tid >> 8;          // 0/1
    int l256 = tid & 255;
    int wsub = l256 >> 6;         // wave within set, 0..3
    int lane = tid & 63;
    int wv = tid >> 6;            // wave 0..7
    int c0 = 2 * sset, c1 = c0 + 1;
    int bt0 = blockIdx.x * CPB + c0;
    float thr = st[1], st2 = st[2];

    for (int k = tid; k < CPB * GP * 2; k += TPB) ((float*)Xli)[k] = 0.f;
    if (tid < CPB * 32) ((float*)axb)[tid] = 0.f;
    __syncthreads();

    const float* aty0 = AtyW + (size_t)bt0 * (2 * GP);
    const float* aty1 = aty0 + 2 * GP;

    for (int it = 0; it < NITER; it++) {
        float ax0[NNc], ax1[NNc];
#pragma unroll
        for (int n = 0; n < NNc; n++) { ax0[n] = axb[c0][n]; ax1[n] = axb[c1][n]; }
        float aR0[Nn], aI0[Nn], aR1[Nn], aI1[Nn];
#pragma unroll
        for (int k = 0; k < Nn; k++) { aR0[k] = 0.f; aI0[k] = 0.f; aR1[k] = 0.f; aI1[k] = 0.f; }

        for (int stp = 0; stp < 19; stp++) {
            int gbase = stp * 256 + l256;
            int chunk = (stp << 2) + wsub;
            const float* pR = ArW + chunk * 960 + lane;
            const float* pI = AiW + chunk * 960 + lane;
            float ar[Nn], ai[Nn];
#pragma unroll
            for (int k = 0; k < Nn; k++) { ar[k] = pR[k * 64]; ai[k] = pI[k * 64]; }
            float2 t0 = *(const float2*)(aty0 + 2 * gbase);
            float2 t1 = *(const float2*)(aty1 + 2 * gbase);
            float2 x0 = *(const float2*)(&Xli[c0][2 * gbase]);
            float2 x1 = *(const float2*)(&Xli[c1][2 * gbase]);
            // v = x + step*Aty - step/30 * A^T(Ax): accumulate negated dot
            float vr0 = x0.x + t0.x, vi0 = x0.y + t0.y;
            float vr1 = x1.x + t1.x, vi1 = x1.y + t1.y;
#pragma unroll
            for (int k = 0; k < Nn; k++) {
                vr0 = fmaf(-ar[k], ax0[k], vr0);
                vr0 = fmaf(-ai[k], ax0[Nn + k], vr0);
                vi0 = fmaf(ai[k], ax0[k], vi0);
                vi0 = fmaf(-ar[k], ax0[Nn + k], vi0);
                vr1 = fmaf(-ar[k], ax1[k], vr1);
                vr1 = fmaf(-ai[k], ax1[Nn + k], vr1);
                vi1 = fmaf(ai[k], ax1[k], vi1);
                vi1 = fmaf(-ar[k], ax1[Nn + k], vi1);
            }
            float m;
            m = fabsf(vr0) - thr; float xr0 = (m > 0.f) ? copysignf(m, vr0) : 0.f;
            m = fabsf(vi0) - thr; float xi0 = (m > 0.f) ? copysignf(m, vi0) : 0.f;
            m = fabsf(vr1) - thr; float xr1 = (m > 0.f) ? copysignf(m, vr1) : 0.f;
            m = fabsf(vi1) - thr; float xi1 = (m > 0.f) ? copysignf(m, vi1) : 0.f;
            *(float2*)(&Xli[c0][2 * gbase]) = make_float2(xr0, xi0);
            *(float2*)(&Xli[c1][2 * gbase]) = make_float2(xr1, xi1);
#pragma unroll
            for (int k = 0; k < Nn; k++) {
                aR0[k] = fmaf(ar[k], xr0, aR0[k]);
                aR0[k] = fmaf(-ai[k], xi0, aR0[k]);
                aI0[k] = fmaf(ai[k], xr0, aI0[k]);
                aI0[k] = fmaf(ar[k], xi0, aI0[k]);
                aR1[k] = fmaf(ar[k], xr1, aR1[k]);
                aR1[k] = fmaf(-ai[k], xi1, aR1[k]);
                aI1[k] = fmaf(ai[k], xr1, aI1[k]);
                aI1[k] = fmaf(ar[k], xi1, aI1[k]);
            }
        }
        if (it == NITER - 1) break;
        // wave-level reduce of the 60 accumulators
#pragma unroll
        for (int k = 0; k < Nn; k++) {
            for (int o = 32; o; o >>= 1) {
                aR0[k] += __shfl_xor(aR0[k], o);
                aI0[k] += __shfl_xor(aI0[k], o);
                aR1[k] += __shfl_xor(aR1[k], o);
                aI1[k] += __shfl_xor(aI1[k], o);
            }
        }
        if (lane == 0) {
#pragma unroll
            for (int k = 0; k < Nn; k++) {
                red[wv][k] = aR0[k];
                red[wv][Nn + k] = aI0[k];
                red[wv][30 + k] = aR1[k];
                red[wv][45 + k] = aI1[k];
            }
        }
        __syncthreads();
        if (tid < CPB * NNc) {
            int c = tid / NNc, n = tid - c * NNc;
            int s4 = (c >> 1) * 4, off = (c & 1) * 30 + n;
            axb[c][n] = st2 * (red[s4][off] + red[s4 + 1][off] +
                               red[s4 + 2][off] + red[s4 + 3][off]);
        }
        __syncthreads();
    }
    __syncthreads();

    // writeback X (layout Xg[bt][G2c]: real at g, imag at Gg+g) + column norms
    for (int c = 0; c < CPB; c++) {
        int bt = blockIdx.x * CPB + c;
        float na = 0.f;
        for (int g = tid; g < Gg; g += TPB) {
            float2 xv = *(const float2*)(&Xli[c][2 * g]);
            Xg[(size_t)bt * G2c + g] = xv.x;
            Xg[(size_t)bt * G2c + Gg + g] = xv.y;
            na += sqrtf(fmaf(xv.x, xv.x, fmaf(xv.y, xv.y, 1e-12f)));
        }
        for (int o = 32; o; o >>= 1) na += __shfl_xor(na, o);
        if (lane == 0) red[wv][c] = na;
    }
    __syncthreads();
    if (tid < CPB) {
        float s = 0.f;
        for (int w = 0; w < 8; w++) s += red[w][tid];
        norms_g[blockIdx.x * CPB + tid] = s;
    }
}

// ---------------- epilogue kernels ----------------

__global__ __launch_bounds__(832) void argmin_kernel(const float* __restrict__ norms_g,
                                                     int* __restrict__ midx) {
    __shared__ float norms[BTc];
    int tid = threadIdx.x;
    if (tid < BTc) norms[tid] = norms_g[tid];
    __syncthreads();
    if (tid < Bb) {
        float best = norms[tid * Tt];
        int bi = 0;
        for (int t = 1; t < Tt; t++) {
            float v = norms[tid * Tt + t];
            if (v < best) { best = v; bi = t; }
        }
        midx[tid] = bi;
    }
}

// s[b][g] = (1/16) * sum_j sqrt(x[g][b*50+tj]^2 + x[G+g][b*50+tj]^2 + 1e-12)
__global__ void s_kernel(const float* __restrict__ Xg, const int* __restrict__ midx,
                         float* __restrict__ out_s) {
    __shared__ int mi[Bb];
    if (threadIdx.x < Bb) mi[threadIdx.x] = midx[threadIdx.x];
    __syncthreads();
    int idx = blockIdx.x * 256 + threadIdx.x;
    if (idx >= Bb * Gg) return;
    int b = idx / Gg, g = idx - b * Gg;
    float acc = 0.f;
#pragma unroll
    for (int j = 0; j < Bb; j++) {
        int bt = b * Tt + mi[j];
        float xr = Xg[(size_t)bt * G2c + g];
        float xi = Xg[(size_t)bt * G2c + Gg + g];
        acc += sqrtf(fmaf(xr, xr, fmaf(xi, xi, 1e-12f)));
    }
    out_s[idx] = acc * (1.f / 16.f);
}

__device__ __forceinline__ bool better_pair(float v, int i, float bv, int bi) {
    return (v > bv) || (v == bv && i < bi);
}

// Stable top-2 per batch (lax.top_k semantics: descending, ties -> lower index)
__global__ void top2_kernel(const float* __restrict__ out_s, const float* __restrict__ angles,
                            const float* __restrict__ ranges, float* __restrict__ out) {
    int b = blockIdx.x, tid = threadIdx.x;
    const float* sb = out_s + (size_t)b * Gg;
    float v1 = -INFINITY, v2 = -INFINITY;
    int i1 = 0x7fffffff, i2 = 0x7fffffff;
    for (int g = tid; g < Gg; g += 256) {
        float v = sb[g];
        if (better_pair(v, g, v1, i1)) { v2 = v1; i2 = i1; v1 = v; i1 = g; }
        else if (better_pair(v, g, v2, i2)) { v2 = v; i2 = g; }
    }
    __shared__ float sv1[256], sv2[256];
    __shared__ int si1[256], si2[256];
    sv1[tid] = v1; si1[tid] = i1; sv2[tid] = v2; si2[tid] = i2;
    __syncthreads();
    for (int stp = 128; stp > 0; stp >>= 1) {
        if (tid < stp) {
            float a1 = sv1[tid], a2 = sv2[tid];
            int ai1 = si1[tid], ai2 = si2[tid];
            float b1 = sv1[tid + stp], b2 = sv2[tid + stp];
            int bi1 = si1[tid + stp], bi2 = si2[tid + stp];
            float n1, n2;
            int ni1, ni2;
            if (better_pair(b1, bi1, a1, ai1)) {
                n1 = b1; ni1 = bi1;
                if (better_pair(a1, ai1, b2, bi2)) { n2 = a1; ni2 = ai1; }
                else { n2 = b2; ni2 = bi2; }
            } else {
                n1 = a1; ni1 = ai1;
                if (better_pair(b1, bi1, a2, ai2)) { n2 = b1; ni2 = bi1; }
                else { n2 = a2; ni2 = ai2; }
            }
            sv1[tid] = n1; si1[tid] = ni1; sv2[tid] = n2; si2[tid] = ni2;
        }
        __syncthreads();
    }
    if (tid == 0) {
        int ia = si1[0], ib2 = si2[0];
        out[b * 2 + 0] = angles[ia / NRANGES];
        out[b * 2 + 1] = angles[ib2 / NRANGES];
        out[32 + b * 2 + 0] = ranges[ia % NRANGES];
        out[32 + b * 2 + 1] = ranges[ib2 % NRANGES];
    }
}

// ---------------- launch ----------------

extern "C" void kernel_launch(void* const* d_in, const int* in_sizes, int n_in,
                              void* d_out, int out_size, void* d_ws, size_t ws_size,
                              hipStream_t stream) {
    const float* yr = (const float*)d_in[0];      // [16,15,50]
    const float* yi = (const float*)d_in[1];      // [16,15,50]
    const float* Ar = (const float*)d_in[2];      // [15,4840]
    const float* Ai = (const float*)d_in[3];      // [15,4840]
    const float* angles = (const float*)d_in[4];  // [121]
    const float* ranges = (const float*)d_in[5];  // [40]
    float* out = (float*)d_out;                   // 32 doa + 32 rng + 77440 s
    float* w = (float*)d_ws;

    // workspace layout (floats), ~62.5 MB total
    size_t oArW = 0;                               // 76*960 = 72960
    size_t oAiW = oArW + (size_t)G64 * 960;        // 72960
    size_t oM30 = oAiW + (size_t)G64 * 960;        // 900 doubles (byte ofs 8-aligned)
    size_t oSt = oM30 + 1800;                      // 8
    size_t oAtyW = oSt + 8;                        // 800*2*4864 = 7782400
    size_t oXg = oAtyW + (size_t)BTc * 2 * GP;     // 800*9680 = 7744000
    size_t oNrm = oXg + (size_t)BTc * G2c;         // 800
    size_t oMidx = oNrm + BTc;                     // 16 ints

    float* ArW = w + oArW;
    float* AiW = w + oAiW;
    double* M30 = (double*)(w + oM30);
    float* st = w + oSt;
    float* AtyW = w + oAtyW;
    float* Xg = w + oXg;
    float* norms_g = w + oNrm;
    int* midx = (int*)(w + oMidx);

    repack_a_kernel<<<(G64 * 960 + 255) / 256, 256, 0, stream>>>(Ar, Ai, ArW, AiW);
    gram_kernel<<<NNc * NNc, 256, 0, stream>>>(Ar, Ai, M30);
    step_kernel<<<1, 1024, 0, stream>>>(M30, st);
    atys_kernel<<<BTc, 256, 0, stream>>>(Ar, Ai, yr, yi, st, AtyW);

    ista_kernel<<<NB, TPB, 0, stream>>>(ArW, AiW, AtyW, st, Xg, norms_g);

    argmin_kernel<<<1, 832, 0, stream>>>(norms_g, midx);
    s_kernel<<<(Bb * Gg + 255) / 256, 256, 0, stream>>>(Xg, midx, out + 64);
    top2_kernel<<<Bb, 256, 0, stream>>>(out + 64, angles, ranges, out);
}